// Round 4
// baseline (68.570 us; speedup 1.0000x reference)
//
#include <hip/hip_runtime.h>

// Problem constants (reference: B=128, S=2048, D=128)
#define BB 128
#define SS 2048
#define DD 128
#define BS (BB * SS)
#define GATHER_BLOCKS 8192
#define ROWS_PER_BLK 8          // rows per block per iteration
#define GATHER_ITERS 8          // 8192 * 8 * 8 == 2*BS == 524288 rows exactly

typedef float f4 __attribute__((ext_vector_type(4)));   // native vector type

// ---------------------------------------------------------------------------
// Kernel A (prep): build pe[S][D] AND visited_time (inverse permutation).
//   vt[half][b][ sol[b][i] ] = i   (random 4B writes, L2-resident 2MB array)
// pe via exp2f instead of powf: 10000^(-2*(j/2)/D) = exp2(-log2(1e4)*(j/2)/64)
// ---------------------------------------------------------------------------
__global__ __launch_bounds__(256) void prep_kernel(
        const int* __restrict__ sol, const int* __restrict__ best,
        float* __restrict__ pe, int* __restrict__ vt) {
    int idx = blockIdx.x * 256 + threadIdx.x;

    if (idx < SS * DD) {
        int s = idx >> 7;          // row
        int j = idx & (DD - 1);    // col
        // log2(10000) = 13.287712379549449
        float invf = exp2f(-13.287712379549449f * (float)(j >> 1) * (1.0f / 64.0f));
        float angle = (float)(s + 1) * invf;
        pe[idx] = (s == 0) ? angle : ((j & 1) ? cosf(angle) : sinf(angle));
    }

    if (idx < 2 * BS) {
        int half = (idx >= BS) ? 1 : 0;
        int k    = half ? idx - BS : idx;     // b*S + i
        int i    = k & (SS - 1);
        int node = half ? best[k] : sol[k];
        vt[half * BS + (k - i) + node] = i;   // visited_time[b][node] = i
    }
}

// ---------------------------------------------------------------------------
// Kernel B (gather): out[r][:] = pe[vt[r]][:], sequential output writes.
// All 64 vt values a block needs are preloaded to LDS up front, so the main
// loop has no dependent scalar load. Output uses nontemporal stores (written
// once, never read) to keep L2 free for the random pe row reads.
// ---------------------------------------------------------------------------
__global__ __launch_bounds__(256) void gather_kernel(
        const int* __restrict__ vt, const float* __restrict__ pe,
        float* __restrict__ out) {
    __shared__ int svt[ROWS_PER_BLK * GATHER_ITERS];   // 64 ints

    const int t = threadIdx.x;
    if (t < ROWS_PER_BLK * GATHER_ITERS) {
        const int it  = t >> 3;          // /ROWS_PER_BLK
        const int rib = t & 7;
        svt[t] = vt[blockIdx.x * ROWS_PER_BLK + rib + it * (GATHER_BLOCKS * ROWS_PER_BLK)];
    }
    __syncthreads();

    const int lane = t & 31;             // 32 lanes per row (float4 each)
    const int rib  = t >> 5;             // 8 rows per 256-thread block
    const f4* __restrict__ pe4 = (const f4*)pe;

    #pragma unroll
    for (int it = 0; it < GATHER_ITERS; ++it) {
        const int r = blockIdx.x * ROWS_PER_BLK + rib + it * (GATHER_BLOCKS * ROWS_PER_BLK);
        const int i = svt[it * ROWS_PER_BLK + rib];
        const f4 v = pe4[i * (DD / 4) + lane];
        __builtin_nontemporal_store(v, (f4*)(out + (size_t)r * DD) + lane);
    }
}

// ---------------------------------------------------------------------------
// Fallback (ws too small): direct scatter with on-the-fly trig.
// ---------------------------------------------------------------------------
__global__ __launch_bounds__(256) void scatter_fused_kernel(
        const int* __restrict__ sol, const int* __restrict__ best,
        float* __restrict__ out) {
    const int ROWS = 2 * BS;
    const int lane = threadIdx.x & 31;
    const int rib  = threadIdx.x >> 5;
    for (int r = blockIdx.x * 8 + rib; r < ROWS; r += gridDim.x * 8) {
        const int half = (r >= BS) ? 1 : 0;
        const int idx  = half ? (r - BS) : r;
        const int i    = idx & (SS - 1);
        const int node = half ? best[idx] : sol[idx];
        const int dstRow = half * BS + (idx - i) + node;
        f4 v;
        #pragma unroll
        for (int q = 0; q < 4; ++q) {
            int j = lane * 4 + q;
            float invf = exp2f(-13.287712379549449f * (float)(j >> 1) * (1.0f / 64.0f));
            float angle = (float)(i + 1) * invf;
            if (i == 0) v[q] = angle;
            else        v[q] = (j & 1) ? cosf(angle) : sinf(angle);
        }
        ((f4*)(out + (size_t)dstRow * DD))[lane] = v;
    }
}

extern "C" void kernel_launch(void* const* d_in, const int* in_sizes, int n_in,
                              void* d_out, int out_size, void* d_ws, size_t ws_size,
                              hipStream_t stream) {
    // inputs: d_in[0] = x (f32, unused), d_in[1] = solutions, d_in[2] = best_solutions
    const int* sol  = (const int*)d_in[1];
    const int* best = (const int*)d_in[2];
    float* out = (float*)d_out;

    const size_t peBytes = (size_t)SS * DD * sizeof(float);     // 1 MiB
    const size_t vtBytes = (size_t)2 * BS * sizeof(int);        // 2 MiB

    if (ws_size >= peBytes + vtBytes) {
        float* pe = (float*)d_ws;
        int*   vt = (int*)((char*)d_ws + peBytes);
        prep_kernel<<<2048, 256, 0, stream>>>(sol, best, pe, vt);
        gather_kernel<<<GATHER_BLOCKS, 256, 0, stream>>>(vt, pe, out);
    } else {
        scatter_fused_kernel<<<8192, 256, 0, stream>>>(sol, best, out);
    }
    (void)in_sizes; (void)n_in; (void)out_size;
}

// Round 5
// 45.960 us; speedup vs baseline: 1.4919x; 1.4919x over previous
//
#include <hip/hip_runtime.h>
#include <math.h>

// Problem constants (reference: B=128, S=2048, D=128)
#define BB 128
#define SS 2048
#define DD 128
#define BS (BB * SS)              // 262144 rows per half
#define BLOCKS 8192               // 8192 blocks * 8 rows = 65536 base rows
#define ROWSTRIDE (BLOCKS * 8)    // 65536; 65536 % SS == 0 -> i invariant

typedef float f4 __attribute__((ext_vector_type(4)));

// ---------------------------------------------------------------------------
// Single fused kernel.
// Each 32-lane group owns base row `base = blockIdx*8 + rib` and handles rows
// base + it*65536 for it=0..3 in both halves (solutions / best_solutions).
// Since 65536 % 2048 == 0, the pe row index i = base & 2047 is loop-invariant:
// each thread computes its 4 pe values ONCE (2 sincos pairs) in registers,
// then issues 8 independent scattered 512B row writes.
//   out[half][b][node][:] = pe[i][:],  node = perm[half][b*S + i]
// ---------------------------------------------------------------------------
__global__ __launch_bounds__(256) void fused_scatter_kernel(
        const int* __restrict__ sol, const int* __restrict__ best,
        float* __restrict__ out) {
    const int t    = threadIdx.x;
    const int lane = t & 31;            // 32 lanes/row, f4 each = 512 B
    const int rib  = t >> 5;            // 8 rows per 256-thread block
    const int base = blockIdx.x * 8 + rib;   // in [0, 65536)
    const int i    = base & (SS - 1);        // pe row, invariant across loop

    // pe values for j = 4*lane + {0,1,2,3}:
    //   j>>1 = 2*lane (q=0,1) and 2*lane+1 (q=2,3)
    //   invf = 10000^(-(j>>1)/64) = exp2(-log2(1e4)/64 * (j>>1))
    const float c = -13.287712379549449f / 64.0f;   // -log2(10000)/64
    const float invf0 = exp2f(c * (float)(2 * lane));
    const float invf1 = exp2f(c * (float)(2 * lane + 1));
    const float a0 = (float)(i + 1) * invf0;
    const float a1 = (float)(i + 1) * invf1;
    f4 v;
    if (i == 0) {               // reference quirk: row 0 stays raw angle
        v[0] = a0; v[1] = a0; v[2] = a1; v[3] = a1;
    } else {
        float s0, c0, s1, c1;
        sincosf(a0, &s0, &c0);
        sincosf(a1, &s1, &c1);
        v[0] = s0; v[1] = c0; v[2] = s1; v[3] = c1;
    }

    // 8 scattered row writes (2 halves x 4 strided rows), indices independent
    #pragma unroll
    for (int h = 0; h < 2; ++h) {
        const int* __restrict__ perm = h ? best : sol;
        float* __restrict__ outh = out + (size_t)h * BS * DD;
        #pragma unroll
        for (int it = 0; it < 4; ++it) {
            const int k    = base + it * ROWSTRIDE;   // b*S + i
            const int node = perm[k];                 // uniform per 32-lane group
            const int dstRow = (k - i) + node;        // b*S + node
            ((f4*)(outh + (size_t)dstRow * DD))[lane] = v;
        }
    }
}

extern "C" void kernel_launch(void* const* d_in, const int* in_sizes, int n_in,
                              void* d_out, int out_size, void* d_ws, size_t ws_size,
                              hipStream_t stream) {
    // inputs: d_in[0] = x (f32, unused), d_in[1] = solutions, d_in[2] = best_solutions
    const int* sol  = (const int*)d_in[1];
    const int* best = (const int*)d_in[2];
    float* out = (float*)d_out;

    fused_scatter_kernel<<<BLOCKS, 256, 0, stream>>>(sol, best, out);

    (void)in_sizes; (void)n_in; (void)out_size; (void)d_ws; (void)ws_size;
}